// Round 14
// baseline (1202.942 us; speedup 1.0000x reference)
//
#include <hip/hip_runtime.h>
#include <hip/hip_bf16.h>
#include <math.h>

#define INF_ 1e10f
#define LGKM0() asm volatile("s_waitcnt lgkmcnt(0)" ::: "memory")

static constexpr int B_  = 64;
static constexpr int N_  = 197;
static constexpr int C_  = 768;
static constexpr int H_  = 12;
static constexpr int T_  = 196;   // N-1 tokens clustered
static constexpr int KC_ = 98;    // NUM_CLUSTERS
static constexpr int KT_ = 99;    // NUM_CLUSTERS + 1
static constexpr int HF_ = 3072;

static constexpr int N_LN1    = B_*N_;  // 12608 LN rows
static constexpr int N_PREP   = 192 + 1728 + 576 + 2304 + 2304;  // 7104
static constexpr int N_METRIC = 788;    // 788*16 = 12608 rows
static constexpr int N_QKV    = 1782;   // 18 x 99 tiles
static constexpr int N_ATTN   = 768;    // 12 heads x 64 batches

typedef __attribute__((ext_vector_type(8))) short short8v;
typedef __attribute__((ext_vector_type(4))) float f32x4;
typedef __attribute__((ext_vector_type(4))) int int4v;

__device__ __forceinline__ float wave_sum(float v){
#pragma unroll
  for(int o=32;o;o>>=1) v += __shfl_down(v,o);
  return v;
}

__device__ __forceinline__ ushort f2bf(float v){
  __hip_bfloat16 t = __float2bfloat16(v);
  return *reinterpret_cast<const ushort*>(&t);
}

// Monotone float->u32 (total order matches float <). Key = (val, row, col) lexicographic.
__device__ __forceinline__ unsigned long long packkey(float v, int r, int a){
  unsigned int bb = __float_as_uint(v);
  bb ^= (bb & 0x80000000u) ? 0xFFFFFFFFu : 0x80000000u;
  return ((unsigned long long)bb<<32) | (unsigned)(r<<8) | (unsigned)a;
}
__device__ __forceinline__ float unpackval(unsigned long long key){
  unsigned u = (unsigned)(key>>32);
  u = (u & 0x80000000u) ? (u ^ 0x80000000u) : ~u;
  return __uint_as_float(u);
}

// ---------------- LN body (row = 768, 256 thr); writes f32 and/or bf16 ----------------
__device__ void ln_body(const float* __restrict__ in,
    const float* __restrict__ g, const float* __restrict__ bb,
    float* __restrict__ outf, __hip_bfloat16* __restrict__ outb, int row,
    float* sred, float* sm2){
  int tid = threadIdx.x;
  const float* xr = in + (size_t)row*C_;
  float v0=xr[tid], v1=xr[tid+256], v2=xr[tid+512];
  float s = wave_sum(v0+v1+v2);
  int w=tid>>6, l=tid&63;
  if(l==0) sred[w]=s;
  __syncthreads();
  if(tid==0) sm2[0] = (sred[0]+sred[1]+sred[2]+sred[3])/(float)C_;
  __syncthreads();
  float m = sm2[0];
  float d0=v0-m, d1=v1-m, d2=v2-m;
  float q = wave_sum(d0*d0+d1*d1+d2*d2);
  if(l==0) sred[w]=q;
  __syncthreads();
  if(tid==0) sm2[1] = (sred[0]+sred[1]+sred[2]+sred[3])/(float)C_;
  __syncthreads();
  float sq = sqrtf(sm2[1] + 1e-5f);
  float y0 = d0/sq*g[tid]     + bb[tid];
  float y1 = d1/sq*g[tid+256] + bb[tid+256];
  float y2 = d2/sq*g[tid+512] + bb[tid+512];
  if(outf){
    float* orow = outf + (size_t)row*C_;
    orow[tid]=y0; orow[tid+256]=y1; orow[tid+512]=y2;
  }
  if(outb){
    __hip_bfloat16* orow = outb + (size_t)row*C_;
    orow[tid]=__float2bfloat16(y0); orow[tid+256]=__float2bfloat16(y1); orow[tid+512]=__float2bfloat16(y2);
  }
}

__global__ __launch_bounds__(256) void ln_kernel(const float* __restrict__ in,
    const float* __restrict__ g, const float* __restrict__ bb,
    float* __restrict__ outf, __hip_bfloat16* __restrict__ outb){
  __shared__ float sred[4];
  __shared__ float sm2[2];
  ln_body(in, g, bb, outf, outb, blockIdx.x, sred, sm2);
}

// ---------------- fused LN1 + prep (wmean + 4 weight transposes); zeroes ctrs ----------------
__global__ __launch_bounds__(256) void ln_prep_kernel(const float* __restrict__ x,
    const float* __restrict__ n1_g, const float* __restrict__ n1_b,
    float* __restrict__ h, __hip_bfloat16* __restrict__ hb,
    const float* __restrict__ w_qkv, const float* __restrict__ w_proj,
    const float* __restrict__ w_fc1, const float* __restrict__ w_fc2,
    float* __restrict__ Wm, __hip_bfloat16* __restrict__ wqkvT,
    __hip_bfloat16* __restrict__ wprojT, __hip_bfloat16* __restrict__ wfc1T,
    __hip_bfloat16* __restrict__ wfc2T, int* __restrict__ ctrs){
  __shared__ union { struct { float sred[4]; float sm2[2]; } l; float tile[32][33]; } sh;
  int bid = blockIdx.x;
  int tid = threadIdx.x;
  if(bid < N_LN1){
    if(bid==0 && tid<8) ctrs[tid]=0;
    ln_body(x, n1_g, n1_b, h, hb, bid, sh.l.sred, sh.l.sm2);
    return;
  }
  bid -= N_LN1;
  if(bid < 192){
    int t = bid*256 + tid;   // t = c*64+d
    if(t >= C_*64) return;
    int c = t>>6, d = t&63;
    const float* p = w_qkv + (size_t)c*(3*C_) + C_ + d;
    float s=0.f;
#pragma unroll
    for(int hh=0;hh<H_;hh++) s += p[hh*64];
    Wm[t] = s*(1.0f/12.0f);
    return;
  }
  bid -= 192;
  const float* w; __hip_bfloat16* wt; int K, N, nbx;
  if(bid < 1728){ w=w_qkv; wt=wqkvT; K=C_; N=3*C_; nbx=72; }
  else if(bid < 1728+576){ bid-=1728; w=w_proj; wt=wprojT; K=C_; N=C_; nbx=24; }
  else if(bid < 1728+576+2304){ bid-=1728+576; w=w_fc1; wt=wfc1T; K=C_; N=HF_; nbx=96; }
  else { bid-=1728+576+2304; w=w_fc2; wt=wfc2T; K=HF_; N=C_; nbx=24; }
  int n0 = (bid%nbx)*32, k0 = (bid/nbx)*32;
  int tx = tid&31, ty = tid>>5;
  for(int r=ty;r<32;r+=8) sh.tile[r][tx] = w[(size_t)(k0+r)*N + n0+tx];
  __syncthreads();
  for(int r=ty;r<32;r+=8) wt[(size_t)(n0+r)*K + k0+tx] = __float2bfloat16(sh.tile[tx][r]);
}

// ---------------- shared-memory structs ----------------
struct ClusterSh {
  float D[T_][T_+1];
  unsigned long long rowkey[T_];
  unsigned long long gkey[2][4];
  unsigned long long scratch[4];
  float sizes[T_];
  int labels[T_];
  int active[T_];
  int rlist[T_];
  int rcnt;
};
struct AttnSh {
  ushort Ks[208][72];
  ushort VsT[64][232];
  ushort Ps[4][16][232];
  float lsz[208];
};
struct GemmSh { ushort As[128][32]; ushort Bs[128][32]; };
struct MetricSh { float hs[16][C_]; };
union FusedSh { ClusterSh c; AttnSh a; GemmSh g; MetricSh m; };

// ---------------- bf16 MFMA GEMM body (global_load_lds staging, linear LDS) ----------------
// EPI: 1/3 = (res+v)+bias -> f32; 2 = v+bias, exact GELU -> bf16; 4 = store bf16
template<int EPI>
__device__ void gemm_body(GemmSh& S, const ushort* __restrict__ A,
    const ushort* __restrict__ Bt, const float* __restrict__ bias,
    const float* __restrict__ res, void* __restrict__ Cout,
    int M, int N, int K, int bx, int by){
  constexpr int BM=128, BN=128, BK=32;
  int tid = threadIdx.x;
  int bm = by*BM, bn = bx*BN;
  int w = tid>>6, l = tid&63;
  int wm = (w>>1)*64, wn = (w&1)*64;
  int lr = l&15, lc = l>>4;           // frag row/col, k-chunk
  f32x4 acc[4][4] = {};
  for(int k0=0;k0<K;k0+=BK){
#pragma unroll
    for(int s=0;s<2;s++){
      int c = s*256 + tid;            // 16B chunk id, 0..511; r=c>>2, q=c&3
      int r = c>>2, q = c&3;
      if(bm + r < M){
        const ushort* srcA = A + (size_t)(bm+r)*K + k0 + q*8;
        __builtin_amdgcn_global_load_lds(
            (const __attribute__((address_space(1))) void*)srcA,
            (__attribute__((address_space(3))) void*)((char*)&S.As[0][0] + c*16), 16, 0, 0);
      }
      const ushort* srcB = Bt + (size_t)(bn+r)*K + k0 + q*8;
      __builtin_amdgcn_global_load_lds(
          (const __attribute__((address_space(1))) void*)srcB,
          (__attribute__((address_space(3))) void*)((char*)&S.Bs[0][0] + c*16), 16, 0, 0);
    }
    __syncthreads();                  // drains vmcnt(0) -> LDS ready
    short8v af[4], bfr[4];
#pragma unroll
    for(int f=0; f<4; f++){
      af[f]  = *reinterpret_cast<const short8v*>(&S.As[wm + f*16 + lr][lc*8]);
      bfr[f] = *reinterpret_cast<const short8v*>(&S.Bs[wn + f*16 + lr][lc*8]);
    }
#pragma unroll
    for(int i=0;i<4;i++)
#pragma unroll
      for(int j=0;j<4;j++)
        acc[i][j] = __builtin_amdgcn_mfma_f32_16x16x32_bf16(af[i], bfr[j], acc[i][j], 0,0,0);
    __syncthreads();
  }
#pragma unroll
  for(int i=0;i<4;i++){
    int rbase = bm + wm + i*16 + lc*4;
#pragma unroll
    for(int j=0;j<4;j++){
      int col = bn + wn + j*16 + lr;
#pragma unroll
      for(int r=0;r<4;r++){
        int row = rbase + r;
        if(row >= M) continue;
        size_t idx = (size_t)row*N + col;
        float v = acc[i][j][r];
        if constexpr(EPI==1 || EPI==3) ((float*)Cout)[idx] = (res[idx] + v) + bias[col];
        if constexpr(EPI==2){
          v += bias[col];
          v = 0.5f*v*(1.0f+erff(v*0.70710678118654752f));
          ((__hip_bfloat16*)Cout)[idx] = __float2bfloat16(v);
        }
        if constexpr(EPI==4) ((__hip_bfloat16*)Cout)[idx] = __float2bfloat16(v);
      }
    }
  }
}

template<int EPI>
__global__ __launch_bounds__(256) void gemm_bf16(const ushort* __restrict__ A,
    const ushort* __restrict__ Bt, const float* __restrict__ bias,
    const float* __restrict__ res, void* __restrict__ Cout,
    int M, int N, int K){
  __shared__ GemmSh S;
  gemm_body<EPI>(S, A, Bt, bias, res, Cout, M, N, K, blockIdx.x, blockIdx.y);
}

// ---------------- metric = h @ Wm (f32, sequential k), normalize, drop cls ----------------
__device__ void metric_body(MetricSh& S, const float* __restrict__ h,
    const float* __restrict__ Wm, float* __restrict__ mnorm, int item){
  int row0 = item*16;
  int tid = threadIdx.x;
  int w = tid>>6, l = tid&63;
  for(int t=tid; t<16*C_; t+=256)
    S.hs[t/C_][t%C_] = h[(size_t)row0*C_ + t];
  __syncthreads();
  float a0=0.f,a1=0.f,a2=0.f,a3=0.f;
#pragma unroll 4
  for(int c=0;c<C_;c++){
    float wv = Wm[c*64+l];
    a0 = fmaf(S.hs[w*4+0][c], wv, a0);
    a1 = fmaf(S.hs[w*4+1][c], wv, a1);
    a2 = fmaf(S.hs[w*4+2][c], wv, a2);
    a3 = fmaf(S.hs[w*4+3][c], wv, a3);
  }
  float accs[4] = {a0,a1,a2,a3};
#pragma unroll
  for(int r=0;r<4;r++){
    float acc = accs[r];
    float q = acc*acc;
#pragma unroll
    for(int o=32;o;o>>=1) q += __shfl_xor(q,o);
    float nrm = sqrtf(q);
    int row = row0 + w*4 + r;
    int bb = row / N_, n = row - bb*N_;
    if(n>=1) mnorm[((size_t)bb*T_+(n-1))*64+l] = acc/nrm;
  }
}

// ---------------- attn body: VERBATIM round-9 MFMA attention ----------------
__device__ void attn_body(AttnSh& S, const ushort* __restrict__ qkv,
    const float* __restrict__ attn_size, __hip_bfloat16* __restrict__ xa, int h, int b){
  int tid = threadIdx.x;
  int w = tid>>6, l = tid&63;
  int lr = l&15, lc = l>>4;
  const size_t QROW = 3*C_;
  for(int t=tid; t<208*64; t+=256){
    int n=t>>6, d=t&63;
    ushort v = 0;
    if(n<197) v = qkv[((size_t)(b*N_+n))*QROW + C_ + h*64 + d];
    S.Ks[n][d] = v;
  }
  for(int t=tid; t<232*64; t+=256){
    int n=t>>6, d=t&63;
    ushort v = 0;
    if(n<197) v = qkv[((size_t)(b*N_+n))*QROW + 2*C_ + h*64 + d];
    S.VsT[d][n] = v;
  }
  for(int t=tid;t<208;t+=256) S.lsz[t] = (t<197)? logf(attn_size[b*N_+t]) : 0.f;
  for(int c=l; c<16*24; c+=64){ int rr=c/24, cc=208+(c%24); S.Ps[w][rr][cc]=0; }
  __syncthreads();

  for(int qt=w; qt<13; qt+=4){
    int qrow = min(qt*16 + lr, 196);
    const ushort* qp = qkv + ((size_t)(b*N_+qrow))*QROW + h*64;
    short8v aq0 = *reinterpret_cast<const short8v*>(qp + lc*8);
    short8v aq1 = *reinterpret_cast<const short8v*>(qp + 32 + lc*8);
    float sc[13][4];
#pragma unroll
    for(int t=0;t<13;t++){
      short8v b0 = *reinterpret_cast<const short8v*>(&S.Ks[t*16+lr][lc*8]);
      short8v b1 = *reinterpret_cast<const short8v*>(&S.Ks[t*16+lr][32+lc*8]);
      f32x4 a = {0.f,0.f,0.f,0.f};
      a = __builtin_amdgcn_mfma_f32_16x16x32_bf16(aq0, b0, a, 0,0,0);
      a = __builtin_amdgcn_mfma_f32_16x16x32_bf16(aq1, b1, a, 0,0,0);
      float ls = S.lsz[t*16+lr];
      bool mask = (t==12) && (lr>=5);
#pragma unroll
      for(int r=0;r<4;r++) sc[t][r] = mask ? -1e30f : (a[r]*0.125f + ls);
    }
    float rsum[4];
#pragma unroll
    for(int r=0;r<4;r++){
      float m=-1e30f;
#pragma unroll
      for(int t=0;t<13;t++) m = fmaxf(m, sc[t][r]);
#pragma unroll
      for(int o=1;o<16;o<<=1) m = fmaxf(m, __shfl_xor(m,o));
      float s=0.f;
#pragma unroll
      for(int t=0;t<13;t++){ float p=expf(sc[t][r]-m); sc[t][r]=p; s+=p; }
#pragma unroll
      for(int o=1;o<16;o<<=1) s += __shfl_xor(s,o);
      rsum[r]=s;
    }
#pragma unroll
    for(int t=0;t<13;t++)
#pragma unroll
      for(int r=0;r<4;r++)
        S.Ps[w][lc*4+r][t*16+lr] = f2bf(sc[t][r]);
    LGKM0();
    short8v ap[7];
#pragma unroll
    for(int ks=0;ks<7;ks++) ap[ks] = *reinterpret_cast<const short8v*>(&S.Ps[w][lr][ks*32 + lc*8]);
#pragma unroll
    for(int f=0; f<4; f++){
      f32x4 o = {0.f,0.f,0.f,0.f};
#pragma unroll
      for(int ks=0;ks<7;ks++){
        short8v bv = *reinterpret_cast<const short8v*>(&S.VsT[f*16+lr][ks*32 + lc*8]);
        o = __builtin_amdgcn_mfma_f32_16x16x32_bf16(ap[ks], bv, o, 0,0,0);
      }
#pragma unroll
      for(int r=0;r<4;r++){
        int q = qt*16 + lc*4 + r;
        if(q<197) xa[((size_t)(b*N_+q))*C_ + h*64 + f*16 + lr] = __float2bfloat16(o[r]/rsum[r]);
      }
    }
  }
}

// ---------------- cluster body: VERBATIM round-9 logic (3 barriers/iter) ----------------
__device__ void cluster_body(ClusterSh& S, const float* __restrict__ mnorm,
    int* __restrict__ labs_ws, float* __restrict__ labs_out, int b){
  int tid = threadIdx.x;
  int w = tid>>6, l = tid&63;
  const float* mb = mnorm + (size_t)b*T_*64;

  for(int t=tid;t<T_*T_;t+=256){
    int r=t/T_, c=t%T_;
    float dot=0.0f;
    for(int d=0;d<64;d++) dot += mb[r*64+d]*mb[c*64+d];
    S.D[r][c] = (r==c) ? INF_ : (1.0f - dot);
  }
  for(int t=tid;t<T_;t+=256){ S.sizes[t]=1.0f; S.labels[t]=t; S.active[t]=1; }
  if(tid<8) S.gkey[tid>>2][tid&3] = ~0ULL;
  __syncthreads();
  if(tid<T_){                    // init row minima (strict < -> first col)
    float bvv=INF_; int ba=0;
    for(int c=0;c<T_;c++){ float v=S.D[tid][c]; if(v<bvv){ bvv=v; ba=c; } }
    S.rowkey[tid] = packkey(bvv, tid, ba);
  }
  __syncthreads();

  for(int it=0; it<T_-KC_; it++){
    int p = it&1;
    unsigned long long key = (tid<T_) ? S.rowkey[tid] : ~0ULL;
    atomicMin(&S.gkey[p][w], key);
    if(tid==0) S.rcnt = 0;
    __syncthreads();                   // b1
    unsigned long long g0=S.gkey[p][0], g1=S.gkey[p][1];
    unsigned long long g2=S.gkey[p][2], g3=S.gkey[p][3];
    unsigned long long ga = g0<g1?g0:g1, gb2 = g2<g3?g2:g3;
    unsigned long long g  = ga<gb2?ga:gb2;
    int i = (int)((g>>8)&0xFF);
    int j = (int)(g&0xFF);
    float ni = S.sizes[i], nj = S.sizes[j];
    int k=tid;
    if(k<T_){
      float di=S.D[i][k], dj=S.D[j][k];
      unsigned long long oldkey = S.rowkey[k];
      float oldrm = unpackval(oldkey);
      int oldarg = (int)(oldkey & 0xFF);
      bool kact = (k!=i) && (k!=j) && (S.active[k]!=0);
      float nd = kact ? (ni*di + nj*dj) / (ni+nj) : INF_;
      S.D[i][k]=nd; S.D[k][i]=nd; S.D[j][k]=INF_; S.D[k][j]=INF_;
      if(S.labels[k]==j) S.labels[k]=i;
      if(k==i){
        int q=atomicAdd(&S.rcnt,1); S.rlist[q]=k;
      } else if(k==j){
        S.rowkey[k] = packkey(INF_, k, 0);
      } else if(kact){
        if(oldarg==i){
          if(nd<=oldrm) S.rowkey[k] = packkey(nd, k, i);
          else { int q=atomicAdd(&S.rcnt,1); S.rlist[q]=k; }
        } else if(oldarg==j){
          if(nd<=oldrm) S.rowkey[k] = packkey(nd, k, i);
          else { int q=atomicAdd(&S.rcnt,1); S.rlist[q]=k; }
        } else {
          if(nd<oldrm || (nd==oldrm && i<oldarg)) S.rowkey[k] = packkey(nd, k, i);
        }
      }
    }
    if(tid==0){ S.sizes[i]=ni+nj; S.active[j]=0; }
    if(l==0) atomicExch(&S.gkey[p^1][w], ~0ULL);
    __syncthreads();                   // b2
    int nr = S.rcnt;
    for(int q=w; q<nr; q+=4){
      int rr = S.rlist[q];
      if(l==0) atomicExch(&S.scratch[w], ~0ULL);
      unsigned long long lk = ~0ULL;
      for(int cc=l; cc<T_; cc+=64){
        unsigned long long ck = packkey(S.D[rr][cc], rr, cc);
        if(ck<lk) lk=ck;
      }
      atomicMin(&S.scratch[w], lk);
      LGKM0();
      unsigned long long rk = S.scratch[w];
      if(l==0) S.rowkey[rr] = rk;
    }
    __syncthreads();                   // b3
  }

  if(tid==0){
    int c=0;
    for(int t=0;t<T_;t++){ c += S.active[t]; S.rlist[t]=c-1; }
    labs_ws[b*N_]=0; labs_out[b*N_]=0.0f;
  }
  __syncthreads();
  for(int t=tid;t<T_;t+=256){
    int lab = S.rlist[S.labels[t]] + 1;
    labs_ws[b*N_+1+t] = lab;
    labs_out[b*N_+1+t] = (float)lab;
  }
}

// ---------------- stage2: persistent kernel, deadlock-free under ANY scheduling ----------------
// EVERY block first drains the metric claim-queue (so a block reaches a spin only after
// all items of that stage are claimed by RUNNING blocks -> every spin terminates even if
// only one block is resident; no cross-block spin depends on an unscheduled producer).
// Then blocks [0,64) spin metric_done -> cluster; others: qkv claim-queue -> spin
// qkv_done -> attn claim-queue. Producer release = syncthreads+threadfence+done++;
// consumer acquire = atomic spin + threadfence. ctrs: [0]=metric_done [1]=qkv_done
// [2]=metric_claim [3]=qkv_claim [4]=attn_claim. attn writes xa (aliases hb) only
// after qkv_done==N_QKV (hb fully consumed).
__global__ __launch_bounds__(256) void stage2(
    const float* __restrict__ h, const float* __restrict__ Wm, float* __restrict__ mnorm,
    const ushort* __restrict__ hb, const ushort* __restrict__ wqkvT,
    __hip_bfloat16* __restrict__ qkvb,
    const float* __restrict__ asz, __hip_bfloat16* __restrict__ xa,
    int* __restrict__ labs_ws, float* __restrict__ labs_out, int* __restrict__ ctrs){
  __shared__ FusedSh sh;
  __shared__ int slot;
  int bid = blockIdx.x;
  int tid = threadIdx.x;

  // ---- ALL blocks: drain metric queue ----
  for(;;){
    if(tid==0) slot = atomicAdd(&ctrs[2],1);
    __syncthreads();
    int it = slot;
    __syncthreads();
    if(it >= N_METRIC) break;
    metric_body(sh.m, h, Wm, mnorm, it);
    __syncthreads();
    __threadfence();
    if(tid==0) atomicAdd(&ctrs[0],1);
    __syncthreads();
  }

  if(bid < B_){
    // ---- cluster block: all metric items are claimed-by-running -> spin terminates ----
    if(tid==0){
      while(atomicAdd(&ctrs[0],0) < N_METRIC) __builtin_amdgcn_s_sleep(8);
    }
    __syncthreads();
    __threadfence();
    cluster_body(sh.c, mnorm, labs_ws, labs_out, bid);
    return;
  }

  // ---- worker: qkv GEMM tiles ----
  for(;;){
    if(tid==0) slot = atomicAdd(&ctrs[3],1);
    __syncthreads();
    int it = slot;
    __syncthreads();
    if(it >= N_QKV) break;
    gemm_body<4>(sh.g, hb, wqkvT, nullptr, nullptr, qkvb,
                 B_*N_, 3*C_, C_, it%18, it/18);
    __syncthreads();
    __threadfence();
    if(tid==0) atomicAdd(&ctrs[1],1);
    __syncthreads();
  }
  // ---- wait all qkv tiles done (all claimed by running blocks) ----
  if(tid==0){
    while(atomicAdd(&ctrs[1],0) < N_QKV) __builtin_amdgcn_s_sleep(8);
  }
  __syncthreads();
  __threadfence();
  // ---- worker: attention items ----
  for(;;){
    if(tid==0) slot = atomicAdd(&ctrs[4],1);
    __syncthreads();
    int it = slot;
    __syncthreads();
    if(it >= N_ATTN) break;
    attn_body(sh.a, (const ushort*)qkvb, asz, xa, it%H_, it/H_);
    __syncthreads();
  }
}

// ---------------- weighted-average merge: one block per (chunk of 256 ch, b) ----------------
__global__ __launch_bounds__(256) void merge_kernel(const float* __restrict__ x1,
    const float* __restrict__ asz, const int* __restrict__ labs,
    float* __restrict__ x2, float* __restrict__ size_out){
  int chunk = blockIdx.x;     // 0..2 (C_/256)
  int b = blockIdx.y;
  __shared__ float acc[KT_][256];
  __shared__ int   lab[N_];
  __shared__ float sz[N_];
  __shared__ float ssum[KT_];
  int tid = threadIdx.x;
  for(int t=tid;t<N_;t+=256){ lab[t]=labs[b*N_+t]; sz[t]=asz[b*N_+t]; }
#pragma unroll
  for(int k=0;k<KT_;k++) acc[k][tid]=0.f;
  __syncthreads();
  if(tid<KT_){
    float s=0.f;
    for(int n=0;n<N_;n++) if(lab[n]==tid) s += sz[n];
    ssum[tid]=s;
  }
  int c = chunk*256 + tid;
  const float* xb = x1 + (size_t)b*N_*C_ + c;
  for(int n=0;n<N_;n++){
    float v = xb[(size_t)n*C_];
    int k = lab[n];
    acc[k][tid] += v * sz[n];
  }
  __syncthreads();
  for(int k=0;k<KT_;k++)
    x2[((size_t)(b*KT_+k))*C_ + c] = acc[k][tid] / ssum[k];
  if(chunk==0 && tid<KT_) size_out[b*KT_+tid] = ssum[tid];
}

extern "C" void kernel_launch(void* const* d_in, const int* in_sizes, int n_in,
                              void* d_out, int out_size, void* d_ws, size_t ws_size,
                              hipStream_t stream){
  const float* x      = (const float*)d_in[0];
  const float* asz    = (const float*)d_in[1];
  const float* n1_g   = (const float*)d_in[2];
  const float* n1_b   = (const float*)d_in[3];
  const float* w_qkv  = (const float*)d_in[4];
  const float* w_proj = (const float*)d_in[5];
  const float* b_proj = (const float*)d_in[6];
  const float* n2_g   = (const float*)d_in[7];
  const float* n2_b   = (const float*)d_in[8];
  const float* w_fc1  = (const float*)d_in[9];
  const float* b_fc1  = (const float*)d_in[10];
  const float* w_fc2  = (const float*)d_in[11];
  const float* b_fc2  = (const float*)d_in[12];

  const size_t ROWS = (size_t)B_*N_;        // 12608
  const size_t M2   = (size_t)B_*KT_;       // 6336
  float* ws = (float*)d_ws;

  float* h     = ws;                                    // [ROWS*C] f32 LN1 out; later x1
  float* qkvR  = h + ROWS*C_;                           // region, ROWS*3C floats
  __hip_bfloat16* qkvb = (__hip_bfloat16*)qkvR;         // qkv as bf16 (attn-only consumer)
  float* x2    = qkvR;                                  // [M2*C] alias (qkv dead by merge)
  __hip_bfloat16* h2b = (__hip_bfloat16*)(qkvR + M2*C_);
  __hip_bfloat16* h3b = (__hip_bfloat16*)(qkvR + M2*C_ + M2*C_/2);
  __hip_bfloat16* hb  = (__hip_bfloat16*)(qkvR + ROWS*3*C_);      // [ROWS*C] bf16; later xa
  __hip_bfloat16* xa  = hb;
  float* mnorm = (float*)(hb) + ROWS*C_/2;
  float* Wm    = mnorm + (size_t)B_*T_*64;
  __hip_bfloat16* wqkvT = (__hip_bfloat16*)(Wm + C_*64);
  __hip_bfloat16* wprojT= (__hip_bfloat16*)((float*)wqkvT + (size_t)3*C_*C_/2);
  __hip_bfloat16* wfc1T = (__hip_bfloat16*)((float*)wprojT + (size_t)C_*C_/2);
  __hip_bfloat16* wfc2T = (__hip_bfloat16*)((float*)wfc1T + (size_t)C_*HF_/2);
  int*   labs  = (int*)((float*)wfc2T + (size_t)HF_*C_/2);
  int*   ctrs  = labs + ROWS;                           // 8 ints of counters
  float* x1    = h;

  float* out     = (float*)d_out;
  float* out_sz  = out + M2*C_;
  float* out_lab = out_sz + M2;

  // fused LN1 + prep (block 0 zeroes counters; stream-ordered before stage2)
  ln_prep_kernel<<<dim3(N_LN1 + N_PREP),256,0,stream>>>(x, n1_g, n1_b, h, hb,
      w_qkv, w_proj, w_fc1, w_fc2, Wm, wqkvT, wprojT, wfc1T, wfc2T, ctrs);

  // persistent stage2: metric (all) -> {cluster | qkv -> attn}
  stage2<<<dim3(256),256,0,stream>>>(h, Wm, mnorm, (const ushort*)hb,
      (const ushort*)wqkvT, qkvb, asz, xa, labs, out_lab, ctrs);

  gemm_bf16<1><<<dim3(6,99),256,0,stream>>>((const ushort*)xa, (const ushort*)wprojT,
      b_proj, x, x1, (int)ROWS, C_, C_);
  merge_kernel<<<dim3(3,B_),256,0,stream>>>(x1, asz, labs, x2, out_sz);

  // MLP
  ln_kernel<<<dim3((unsigned)M2),256,0,stream>>>(x2, n2_g, n2_b, nullptr, h2b);
  gemm_bf16<2><<<dim3(24,50),256,0,stream>>>((const ushort*)h2b, (const ushort*)wfc1T,
      b_fc1, nullptr, h3b, (int)M2, HF_, C_);
  gemm_bf16<3><<<dim3(6,50),256,0,stream>>>((const ushort*)h3b, (const ushort*)wfc2T,
      b_fc2, x2, out, (int)M2, C_, HF_);
}

// Round 15
// 982.972 us; speedup vs baseline: 1.2238x; 1.2238x over previous
//
#include <hip/hip_runtime.h>
#include <hip/hip_bf16.h>
#include <math.h>

#define INF_ 1e10f
#define LGKM0() asm volatile("s_waitcnt lgkmcnt(0)" ::: "memory")

static constexpr int B_  = 64;
static constexpr int N_  = 197;
static constexpr int C_  = 768;
static constexpr int H_  = 12;
static constexpr int T_  = 196;   // N-1 tokens clustered
static constexpr int KC_ = 98;    // NUM_CLUSTERS
static constexpr int KT_ = 99;    // NUM_CLUSTERS + 1
static constexpr int HF_ = 3072;

static constexpr int N_LN1  = B_*N_;                           // 12608 LN rows
static constexpr int N_PREP = 192 + 1728 + 576 + 2304 + 2304;  // 7104
static constexpr int N_ATTN = 768;                             // 12 heads x 64 batches
static constexpr int N_PROJ = 6*99;                            // 594 proj tiles (6 x 99)

typedef __attribute__((ext_vector_type(8))) short short8v;
typedef __attribute__((ext_vector_type(4))) float f32x4;
typedef __attribute__((ext_vector_type(4))) int int4v;

__device__ __forceinline__ float wave_sum(float v){
#pragma unroll
  for(int o=32;o;o>>=1) v += __shfl_down(v,o);
  return v;
}

__device__ __forceinline__ ushort f2bf(float v){
  __hip_bfloat16 t = __float2bfloat16(v);
  return *reinterpret_cast<const ushort*>(&t);
}

// Monotone float->u32 (total order matches float <). Key = (val, row, col) lexicographic.
__device__ __forceinline__ unsigned long long packkey(float v, int r, int a){
  unsigned int bb = __float_as_uint(v);
  bb ^= (bb & 0x80000000u) ? 0xFFFFFFFFu : 0x80000000u;
  return ((unsigned long long)bb<<32) | (unsigned)(r<<8) | (unsigned)a;
}
__device__ __forceinline__ float unpackval(unsigned long long key){
  unsigned u = (unsigned)(key>>32);
  u = (u & 0x80000000u) ? (u ^ 0x80000000u) : ~u;
  return __uint_as_float(u);
}

// ---------------- LN body (row = 768, 256 thr); writes f32 and/or bf16 ----------------
__device__ void ln_body(const float* __restrict__ in,
    const float* __restrict__ g, const float* __restrict__ bb,
    float* __restrict__ outf, __hip_bfloat16* __restrict__ outb, int row,
    float* sred, float* sm2){
  int tid = threadIdx.x;
  const float* xr = in + (size_t)row*C_;
  float v0=xr[tid], v1=xr[tid+256], v2=xr[tid+512];
  float s = wave_sum(v0+v1+v2);
  int w=tid>>6, l=tid&63;
  if(l==0) sred[w]=s;
  __syncthreads();
  if(tid==0) sm2[0] = (sred[0]+sred[1]+sred[2]+sred[3])/(float)C_;
  __syncthreads();
  float m = sm2[0];
  float d0=v0-m, d1=v1-m, d2=v2-m;
  float q = wave_sum(d0*d0+d1*d1+d2*d2);
  if(l==0) sred[w]=q;
  __syncthreads();
  if(tid==0) sm2[1] = (sred[0]+sred[1]+sred[2]+sred[3])/(float)C_;
  __syncthreads();
  float sq = sqrtf(sm2[1] + 1e-5f);
  float y0 = d0/sq*g[tid]     + bb[tid];
  float y1 = d1/sq*g[tid+256] + bb[tid+256];
  float y2 = d2/sq*g[tid+512] + bb[tid+512];
  if(outf){
    float* orow = outf + (size_t)row*C_;
    orow[tid]=y0; orow[tid+256]=y1; orow[tid+512]=y2;
  }
  if(outb){
    __hip_bfloat16* orow = outb + (size_t)row*C_;
    orow[tid]=__float2bfloat16(y0); orow[tid+256]=__float2bfloat16(y1); orow[tid+512]=__float2bfloat16(y2);
  }
}

__global__ __launch_bounds__(256) void ln_kernel(const float* __restrict__ in,
    const float* __restrict__ g, const float* __restrict__ bb,
    float* __restrict__ outf, __hip_bfloat16* __restrict__ outb){
  __shared__ float sred[4];
  __shared__ float sm2[2];
  ln_body(in, g, bb, outf, outb, blockIdx.x, sred, sm2);
}

// ---------------- fused LN1 + prep (wmean + 4 weight transposes); zeroes ctrs ----------------
__global__ __launch_bounds__(256) void ln_prep_kernel(const float* __restrict__ x,
    const float* __restrict__ n1_g, const float* __restrict__ n1_b,
    float* __restrict__ h, __hip_bfloat16* __restrict__ hb,
    const float* __restrict__ w_qkv, const float* __restrict__ w_proj,
    const float* __restrict__ w_fc1, const float* __restrict__ w_fc2,
    float* __restrict__ Wm, __hip_bfloat16* __restrict__ wqkvT,
    __hip_bfloat16* __restrict__ wprojT, __hip_bfloat16* __restrict__ wfc1T,
    __hip_bfloat16* __restrict__ wfc2T, int* __restrict__ ctrs){
  __shared__ union { struct { float sred[4]; float sm2[2]; } l; float tile[32][33]; } sh;
  int bid = blockIdx.x;
  int tid = threadIdx.x;
  if(bid < N_LN1){
    if(bid==0 && tid<72) ctrs[tid]=0;
    ln_body(x, n1_g, n1_b, h, hb, bid, sh.l.sred, sh.l.sm2);
    return;
  }
  bid -= N_LN1;
  if(bid < 192){
    int t = bid*256 + tid;   // t = c*64+d
    if(t >= C_*64) return;
    int c = t>>6, d = t&63;
    const float* p = w_qkv + (size_t)c*(3*C_) + C_ + d;
    float s=0.f;
#pragma unroll
    for(int hh=0;hh<H_;hh++) s += p[hh*64];
    Wm[t] = s*(1.0f/12.0f);
    return;
  }
  bid -= 192;
  const float* w; __hip_bfloat16* wt; int K, N, nbx;
  if(bid < 1728){ w=w_qkv; wt=wqkvT; K=C_; N=3*C_; nbx=72; }
  else if(bid < 1728+576){ bid-=1728; w=w_proj; wt=wprojT; K=C_; N=C_; nbx=24; }
  else if(bid < 1728+576+2304){ bid-=1728+576; w=w_fc1; wt=wfc1T; K=C_; N=HF_; nbx=96; }
  else { bid-=1728+576+2304; w=w_fc2; wt=wfc2T; K=HF_; N=C_; nbx=24; }
  int n0 = (bid%nbx)*32, k0 = (bid/nbx)*32;
  int tx = tid&31, ty = tid>>5;
  for(int r=ty;r<32;r+=8) sh.tile[r][tx] = w[(size_t)(k0+r)*N + n0+tx];
  __syncthreads();
  for(int r=ty;r<32;r+=8) wt[(size_t)(n0+r)*K + k0+tx] = __float2bfloat16(sh.tile[tx][r]);
}

// ---------------- shared-memory structs ----------------
struct ClusterSh {
  float D[T_][T_+1];
  unsigned long long rowkey[T_];
  unsigned long long gkey[2][4];
  unsigned long long scratch[4];
  float sizes[T_];
  int labels[T_];
  int active[T_];
  int rlist[T_];
  int rcnt;
};
struct AttnSh {
  ushort Ks[208][72];
  ushort VsT[64][232];
  ushort Ps[4][16][232];
  float lsz[208];
};
struct GemmSh { ushort As[128][32]; ushort Bs[128][32]; };
union FusedSh { ClusterSh c; AttnSh a; GemmSh g; };

// ---------------- bf16 MFMA GEMM body (global_load_lds staging, linear LDS) ----------------
// EPI: 1/3 = (res+v)+bias -> f32; 2 = v+bias, exact GELU -> bf16; 4 = store bf16
template<int EPI>
__device__ void gemm_body(GemmSh& S, const ushort* __restrict__ A,
    const ushort* __restrict__ Bt, const float* __restrict__ bias,
    const float* __restrict__ res, void* __restrict__ Cout,
    int M, int N, int K, int bx, int by){
  constexpr int BM=128, BN=128, BK=32;
  int tid = threadIdx.x;
  int bm = by*BM, bn = bx*BN;
  int w = tid>>6, l = tid&63;
  int wm = (w>>1)*64, wn = (w&1)*64;
  int lr = l&15, lc = l>>4;           // frag row/col, k-chunk
  f32x4 acc[4][4] = {};
  for(int k0=0;k0<K;k0+=BK){
#pragma unroll
    for(int s=0;s<2;s++){
      int c = s*256 + tid;            // 16B chunk id, 0..511; r=c>>2, q=c&3
      int r = c>>2, q = c&3;
      if(bm + r < M){
        const ushort* srcA = A + (size_t)(bm+r)*K + k0 + q*8;
        __builtin_amdgcn_global_load_lds(
            (const __attribute__((address_space(1))) void*)srcA,
            (__attribute__((address_space(3))) void*)((char*)&S.As[0][0] + c*16), 16, 0, 0);
      }
      const ushort* srcB = Bt + (size_t)(bn+r)*K + k0 + q*8;
      __builtin_amdgcn_global_load_lds(
          (const __attribute__((address_space(1))) void*)srcB,
          (__attribute__((address_space(3))) void*)((char*)&S.Bs[0][0] + c*16), 16, 0, 0);
    }
    __syncthreads();                  // drains vmcnt(0) -> LDS ready
    short8v af[4], bfr[4];
#pragma unroll
    for(int f=0; f<4; f++){
      af[f]  = *reinterpret_cast<const short8v*>(&S.As[wm + f*16 + lr][lc*8]);
      bfr[f] = *reinterpret_cast<const short8v*>(&S.Bs[wn + f*16 + lr][lc*8]);
    }
#pragma unroll
    for(int i=0;i<4;i++)
#pragma unroll
      for(int j=0;j<4;j++)
        acc[i][j] = __builtin_amdgcn_mfma_f32_16x16x32_bf16(af[i], bfr[j], acc[i][j], 0,0,0);
    __syncthreads();
  }
#pragma unroll
  for(int i=0;i<4;i++){
    int rbase = bm + wm + i*16 + lc*4;
#pragma unroll
    for(int j=0;j<4;j++){
      int col = bn + wn + j*16 + lr;
#pragma unroll
      for(int r=0;r<4;r++){
        int row = rbase + r;
        if(row >= M) continue;
        size_t idx = (size_t)row*N + col;
        float v = acc[i][j][r];
        if constexpr(EPI==1 || EPI==3) ((float*)Cout)[idx] = (res[idx] + v) + bias[col];
        if constexpr(EPI==2){
          v += bias[col];
          v = 0.5f*v*(1.0f+erff(v*0.70710678118654752f));
          ((__hip_bfloat16*)Cout)[idx] = __float2bfloat16(v);
        }
        if constexpr(EPI==4) ((__hip_bfloat16*)Cout)[idx] = __float2bfloat16(v);
      }
    }
  }
}

template<int EPI>
__global__ __launch_bounds__(256) void gemm_bf16(const ushort* __restrict__ A,
    const ushort* __restrict__ Bt, const float* __restrict__ bias,
    const float* __restrict__ res, void* __restrict__ Cout,
    int M, int N, int K){
  __shared__ GemmSh S;
  gemm_body<EPI>(S, A, Bt, bias, res, Cout, M, N, K, blockIdx.x, blockIdx.y);
}

// ---------------- metric = h @ Wm (f32, sequential k), normalize, drop cls ----------------
__global__ __launch_bounds__(256) void metric_gemm(const float* __restrict__ h,
    const float* __restrict__ Wm, float* __restrict__ mnorm){
  int row0 = blockIdx.x*16;
  __shared__ float hs[16][C_];
  int tid = threadIdx.x;
  int w = tid>>6, l = tid&63;
  for(int t=tid; t<16*C_; t+=256)
    hs[t/C_][t%C_] = h[(size_t)row0*C_ + t];
  __syncthreads();
  float a0=0.f,a1=0.f,a2=0.f,a3=0.f;
#pragma unroll 4
  for(int c=0;c<C_;c++){
    float wv = Wm[c*64+l];
    a0 = fmaf(hs[w*4+0][c], wv, a0);
    a1 = fmaf(hs[w*4+1][c], wv, a1);
    a2 = fmaf(hs[w*4+2][c], wv, a2);
    a3 = fmaf(hs[w*4+3][c], wv, a3);
  }
  float accs[4] = {a0,a1,a2,a3};
#pragma unroll
  for(int r=0;r<4;r++){
    float acc = accs[r];
    float q = acc*acc;
#pragma unroll
    for(int o=32;o;o>>=1) q += __shfl_xor(q,o);
    float nrm = sqrtf(q);
    int row = row0 + w*4 + r;
    int bb = row / N_, n = row - bb*N_;
    if(n>=1) mnorm[((size_t)bb*T_+(n-1))*64+l] = acc/nrm;
  }
}

// ---------------- attn body: VERBATIM round-9 MFMA attention ----------------
__device__ void attn_body(AttnSh& S, const ushort* __restrict__ qkv,
    const float* __restrict__ attn_size, __hip_bfloat16* __restrict__ xa, int h, int b){
  int tid = threadIdx.x;
  int w = tid>>6, l = tid&63;
  int lr = l&15, lc = l>>4;
  const size_t QROW = 3*C_;
  for(int t=tid; t<208*64; t+=256){
    int n=t>>6, d=t&63;
    ushort v = 0;
    if(n<197) v = qkv[((size_t)(b*N_+n))*QROW + C_ + h*64 + d];
    S.Ks[n][d] = v;
  }
  for(int t=tid; t<232*64; t+=256){
    int n=t>>6, d=t&63;
    ushort v = 0;
    if(n<197) v = qkv[((size_t)(b*N_+n))*QROW + 2*C_ + h*64 + d];
    S.VsT[d][n] = v;
  }
  for(int t=tid;t<208;t+=256) S.lsz[t] = (t<197)? logf(attn_size[b*N_+t]) : 0.f;
  for(int c=l; c<16*24; c+=64){ int rr=c/24, cc=208+(c%24); S.Ps[w][rr][cc]=0; }
  __syncthreads();

  for(int qt=w; qt<13; qt+=4){
    int qrow = min(qt*16 + lr, 196);
    const ushort* qp = qkv + ((size_t)(b*N_+qrow))*QROW + h*64;
    short8v aq0 = *reinterpret_cast<const short8v*>(qp + lc*8);
    short8v aq1 = *reinterpret_cast<const short8v*>(qp + 32 + lc*8);
    float sc[13][4];
#pragma unroll
    for(int t=0;t<13;t++){
      short8v b0 = *reinterpret_cast<const short8v*>(&S.Ks[t*16+lr][lc*8]);
      short8v b1 = *reinterpret_cast<const short8v*>(&S.Ks[t*16+lr][32+lc*8]);
      f32x4 a = {0.f,0.f,0.f,0.f};
      a = __builtin_amdgcn_mfma_f32_16x16x32_bf16(aq0, b0, a, 0,0,0);
      a = __builtin_amdgcn_mfma_f32_16x16x32_bf16(aq1, b1, a, 0,0,0);
      float ls = S.lsz[t*16+lr];
      bool mask = (t==12) && (lr>=5);
#pragma unroll
      for(int r=0;r<4;r++) sc[t][r] = mask ? -1e30f : (a[r]*0.125f + ls);
    }
    float rsum[4];
#pragma unroll
    for(int r=0;r<4;r++){
      float m=-1e30f;
#pragma unroll
      for(int t=0;t<13;t++) m = fmaxf(m, sc[t][r]);
#pragma unroll
      for(int o=1;o<16;o<<=1) m = fmaxf(m, __shfl_xor(m,o));
      float s=0.f;
#pragma unroll
      for(int t=0;t<13;t++){ float p=expf(sc[t][r]-m); sc[t][r]=p; s+=p; }
#pragma unroll
      for(int o=1;o<16;o<<=1) s += __shfl_xor(s,o);
      rsum[r]=s;
    }
#pragma unroll
    for(int t=0;t<13;t++)
#pragma unroll
      for(int r=0;r<4;r++)
        S.Ps[w][lc*4+r][t*16+lr] = f2bf(sc[t][r]);
    LGKM0();
    short8v ap[7];
#pragma unroll
    for(int ks=0;ks<7;ks++) ap[ks] = *reinterpret_cast<const short8v*>(&S.Ps[w][lr][ks*32 + lc*8]);
#pragma unroll
    for(int f=0; f<4; f++){
      f32x4 o = {0.f,0.f,0.f,0.f};
#pragma unroll
      for(int ks=0;ks<7;ks++){
        short8v bv = *reinterpret_cast<const short8v*>(&S.VsT[f*16+lr][ks*32 + lc*8]);
        o = __builtin_amdgcn_mfma_f32_16x16x32_bf16(ap[ks], bv, o, 0,0,0);
      }
#pragma unroll
      for(int r=0;r<4;r++){
        int q = qt*16 + lc*4 + r;
        if(q<197) xa[((size_t)(b*N_+q))*C_ + h*64 + f*16 + lr] = __float2bfloat16(o[r]/rsum[r]);
      }
    }
  }
}

// ---------------- cluster body: VERBATIM round-9 logic (3 barriers/iter) ----------------
__device__ void cluster_body(ClusterSh& S, const float* __restrict__ mnorm,
    int* __restrict__ labs_ws, float* __restrict__ labs_out, int b){
  int tid = threadIdx.x;
  int w = tid>>6, l = tid&63;
  const float* mb = mnorm + (size_t)b*T_*64;

  for(int t=tid;t<T_*T_;t+=256){
    int r=t/T_, c=t%T_;
    float dot=0.0f;
    for(int d=0;d<64;d++) dot += mb[r*64+d]*mb[c*64+d];
    S.D[r][c] = (r==c) ? INF_ : (1.0f - dot);
  }
  for(int t=tid;t<T_;t+=256){ S.sizes[t]=1.0f; S.labels[t]=t; S.active[t]=1; }
  if(tid<8) S.gkey[tid>>2][tid&3] = ~0ULL;
  __syncthreads();
  if(tid<T_){                    // init row minima (strict < -> first col)
    float bvv=INF_; int ba=0;
    for(int c=0;c<T_;c++){ float v=S.D[tid][c]; if(v<bvv){ bvv=v; ba=c; } }
    S.rowkey[tid] = packkey(bvv, tid, ba);
  }
  __syncthreads();

  for(int it=0; it<T_-KC_; it++){
    int p = it&1;
    unsigned long long key = (tid<T_) ? S.rowkey[tid] : ~0ULL;
    atomicMin(&S.gkey[p][w], key);
    if(tid==0) S.rcnt = 0;
    __syncthreads();                   // b1
    unsigned long long g0=S.gkey[p][0], g1=S.gkey[p][1];
    unsigned long long g2=S.gkey[p][2], g3=S.gkey[p][3];
    unsigned long long ga = g0<g1?g0:g1, gb2 = g2<g3?g2:g3;
    unsigned long long g  = ga<gb2?ga:gb2;
    int i = (int)((g>>8)&0xFF);
    int j = (int)(g&0xFF);
    float ni = S.sizes[i], nj = S.sizes[j];
    int k=tid;
    if(k<T_){
      float di=S.D[i][k], dj=S.D[j][k];
      unsigned long long oldkey = S.rowkey[k];
      float oldrm = unpackval(oldkey);
      int oldarg = (int)(oldkey & 0xFF);
      bool kact = (k!=i) && (k!=j) && (S.active[k]!=0);
      float nd = kact ? (ni*di + nj*dj) / (ni+nj) : INF_;
      S.D[i][k]=nd; S.D[k][i]=nd; S.D[j][k]=INF_; S.D[k][j]=INF_;
      if(S.labels[k]==j) S.labels[k]=i;
      if(k==i){
        int q=atomicAdd(&S.rcnt,1); S.rlist[q]=k;
      } else if(k==j){
        S.rowkey[k] = packkey(INF_, k, 0);
      } else if(kact){
        if(oldarg==i){
          if(nd<=oldrm) S.rowkey[k] = packkey(nd, k, i);
          else { int q=atomicAdd(&S.rcnt,1); S.rlist[q]=k; }
        } else if(oldarg==j){
          if(nd<=oldrm) S.rowkey[k] = packkey(nd, k, i);
          else { int q=atomicAdd(&S.rcnt,1); S.rlist[q]=k; }
        } else {
          if(nd<oldrm || (nd==oldrm && i<oldarg)) S.rowkey[k] = packkey(nd, k, i);
        }
      }
    }
    if(tid==0){ S.sizes[i]=ni+nj; S.active[j]=0; }
    if(l==0) atomicExch(&S.gkey[p^1][w], ~0ULL);
    __syncthreads();                   // b2
    int nr = S.rcnt;
    for(int q=w; q<nr; q+=4){
      int rr = S.rlist[q];
      if(l==0) atomicExch(&S.scratch[w], ~0ULL);
      unsigned long long lk = ~0ULL;
      for(int cc=l; cc<T_; cc+=64){
        unsigned long long ck = packkey(S.D[rr][cc], rr, cc);
        if(ck<lk) lk=ck;
      }
      atomicMin(&S.scratch[w], lk);
      LGKM0();
      unsigned long long rk = S.scratch[w];
      if(l==0) S.rowkey[rr] = rk;
    }
    __syncthreads();                   // b3
  }

  if(tid==0){
    int c=0;
    for(int t=0;t<T_;t++){ c += S.active[t]; S.rlist[t]=c-1; }
    labs_ws[b*N_]=0; labs_out[b*N_]=0.0f;
  }
  __syncthreads();
  for(int t=tid;t<T_;t+=256){
    int lab = S.rlist[S.labels[t]] + 1;
    labs_ws[b*N_+1+t] = lab;
    labs_out[b*N_+1+t] = (float)lab;
  }
}

// ---------------- stage2: cluster (blocks 0-63) || attn+proj workers (64-255) ----------------
// Workers drain the attn CLAIM-QUEUE first (so any worker reaching the proj spin has seen
// the attn queue exhausted -> all awaited items held by RUNNING blocks -> spins terminate
// under any scheduling). Each attn item (b,h) bumps batch_done[b]; proj tile (bx,by) spins
// until all batches covering its rows have 12 heads done, then runs gemm_body<1> (x1 =
// res + xa@wprojT + bias). Cluster blocks depend only on prior dispatches (no spin).
// ctrs: [4]=attn_claim [5]=proj_claim [8+b]=batch_done. Proj at 1 blk/CU is slow per
// tile but runs entirely in the cluster's ~510us shadow on otherwise-idle CUs.
__global__ __launch_bounds__(256) void stage2(
    const float* __restrict__ mnorm, int* __restrict__ labs_ws, float* __restrict__ labs_out,
    const ushort* __restrict__ qkv, const float* __restrict__ asz,
    __hip_bfloat16* __restrict__ xa,
    const ushort* __restrict__ wprojT, const float* __restrict__ b_proj,
    const float* __restrict__ xres, float* __restrict__ x1,
    int* __restrict__ ctrs){
  __shared__ FusedSh sh;
  __shared__ int slot;
  int bid = blockIdx.x;
  int tid = threadIdx.x;

  if(bid < B_){
    cluster_body(sh.c, mnorm, labs_ws, labs_out, bid);
    return;
  }

  // ---- workers: drain attn claim-queue ----
  for(;;){
    if(tid==0) slot = atomicAdd(&ctrs[4],1);
    __syncthreads();
    int it = slot;
    __syncthreads();
    if(it >= N_ATTN) break;
    attn_body(sh.a, qkv, asz, xa, it%H_, it/H_);
    __syncthreads();
    __threadfence();
    if(tid==0) atomicAdd(&ctrs[8 + it/H_], 1);
    __syncthreads();
  }

  // ---- workers: drain proj claim-queue (per-batch gating) ----
  for(;;){
    if(tid==0) slot = atomicAdd(&ctrs[5],1);
    __syncthreads();
    int it = slot;
    __syncthreads();
    if(it >= N_PROJ) break;
    int bx = it%6, by = it/6;
    int b0 = (by*128)/N_;
    int b1 = min(B_-1, (by*128+127)/N_);
    if(tid==0){
      for(int b=b0;b<=b1;b++)
        while(atomicAdd(&ctrs[8+b],0) < H_) __builtin_amdgcn_s_sleep(8);
    }
    __syncthreads();
    __threadfence();
    gemm_body<1>(sh.g, (const ushort*)xa, wprojT, b_proj, xres, x1,
                 B_*N_, C_, C_, bx, by);
    __syncthreads();
  }
}

// ---------------- weighted-average merge: one block per (chunk of 256 ch, b) ----------------
__global__ __launch_bounds__(256) void merge_kernel(const float* __restrict__ x1,
    const float* __restrict__ asz, const int* __restrict__ labs,
    float* __restrict__ x2, float* __restrict__ size_out){
  int chunk = blockIdx.x;     // 0..2 (C_/256)
  int b = blockIdx.y;
  __shared__ float acc[KT_][256];
  __shared__ int   lab[N_];
  __shared__ float sz[N_];
  __shared__ float ssum[KT_];
  int tid = threadIdx.x;
  for(int t=tid;t<N_;t+=256){ lab[t]=labs[b*N_+t]; sz[t]=asz[b*N_+t]; }
#pragma unroll
  for(int k=0;k<KT_;k++) acc[k][tid]=0.f;
  __syncthreads();
  if(tid<KT_){
    float s=0.f;
    for(int n=0;n<N_;n++) if(lab[n]==tid) s += sz[n];
    ssum[tid]=s;
  }
  int c = chunk*256 + tid;
  const float* xb = x1 + (size_t)b*N_*C_ + c;
  for(int n=0;n<N_;n++){
    float v = xb[(size_t)n*C_];
    int k = lab[n];
    acc[k][tid] += v * sz[n];
  }
  __syncthreads();
  for(int k=0;k<KT_;k++)
    x2[((size_t)(b*KT_+k))*C_ + c] = acc[k][tid] / ssum[k];
  if(chunk==0 && tid<KT_) size_out[b*KT_+tid] = ssum[tid];
}

extern "C" void kernel_launch(void* const* d_in, const int* in_sizes, int n_in,
                              void* d_out, int out_size, void* d_ws, size_t ws_size,
                              hipStream_t stream){
  const float* x      = (const float*)d_in[0];
  const float* asz    = (const float*)d_in[1];
  const float* n1_g   = (const float*)d_in[2];
  const float* n1_b   = (const float*)d_in[3];
  const float* w_qkv  = (const float*)d_in[4];
  const float* w_proj = (const float*)d_in[5];
  const float* b_proj = (const float*)d_in[6];
  const float* n2_g   = (const float*)d_in[7];
  const float* n2_b   = (const float*)d_in[8];
  const float* w_fc1  = (const float*)d_in[9];
  const float* b_fc1  = (const float*)d_in[10];
  const float* w_fc2  = (const float*)d_in[11];
  const float* b_fc2  = (const float*)d_in[12];

  const size_t ROWS = (size_t)B_*N_;        // 12608
  const size_t M2   = (size_t)B_*KT_;       // 6336
  float* ws = (float*)d_ws;

  float* h     = ws;                                    // [ROWS*C] f32 LN1 out; later x1
  float* qkvR  = h + ROWS*C_;                           // region, ROWS*3C floats
  __hip_bfloat16* qkvb = (__hip_bfloat16*)qkvR;         // qkv as bf16 (attn-only consumer)
  float* x2    = qkvR;                                  // [M2*C] alias (qkv dead by merge)
  __hip_bfloat16* h2b = (__hip_bfloat16*)(qkvR + M2*C_);
  __hip_bfloat16* h3b = (__hip_bfloat16*)(qkvR + M2*C_ + M2*C_/2);
  __hip_bfloat16* hb  = (__hip_bfloat16*)(qkvR + ROWS*3*C_);      // [ROWS*C] bf16; later xa
  __hip_bfloat16* xa  = hb;
  float* mnorm = (float*)(hb) + ROWS*C_/2;
  float* Wm    = mnorm + (size_t)B_*T_*64;
  __hip_bfloat16* wqkvT = (__hip_bfloat16*)(Wm + C_*64);
  __hip_bfloat16* wprojT= (__hip_bfloat16*)((float*)wqkvT + (size_t)3*C_*C_/2);
  __hip_bfloat16* wfc1T = (__hip_bfloat16*)((float*)wprojT + (size_t)C_*C_/2);
  __hip_bfloat16* wfc2T = (__hip_bfloat16*)((float*)wfc1T + (size_t)C_*HF_/2);
  int*   labs  = (int*)((float*)wfc2T + (size_t)HF_*C_/2);
  int*   ctrs  = labs + ROWS;                           // 72 ints of counters
  float* x1    = h;

  float* out     = (float*)d_out;
  float* out_sz  = out + M2*C_;
  float* out_lab = out_sz + M2;

  // fused LN1 + prep (block 0 zeroes counters; stream-ordered before stage2)
  ln_prep_kernel<<<dim3(N_LN1 + N_PREP),256,0,stream>>>(x, n1_g, n1_b, h, hb,
      w_qkv, w_proj, w_fc1, w_fc2, Wm, wqkvT, wprojT, wfc1T, wfc2T, ctrs);

  // attention-block inputs (fast multi-block/CU dispatches)
  gemm_bf16<4><<<dim3(18,99),256,0,stream>>>((const ushort*)hb, (const ushort*)wqkvT,
      nullptr, nullptr, qkvb, (int)ROWS, 3*C_, C_);
  metric_gemm<<<dim3(788),256,0,stream>>>(h, Wm, mnorm);

  // stage2: cluster || attn -> proj (proj runs in cluster's shadow)
  stage2<<<dim3(256),256,0,stream>>>(mnorm, labs, out_lab, (const ushort*)qkvb,
      asz, xa, (const ushort*)wprojT, b_proj, x, x1, ctrs);

  merge_kernel<<<dim3(3,B_),256,0,stream>>>(x1, asz, labs, x2, out_sz);

  // MLP
  ln_kernel<<<dim3((unsigned)M2),256,0,stream>>>(x2, n2_g, n2_b, nullptr, h2b);
  gemm_bf16<2><<<dim3(24,50),256,0,stream>>>((const ushort*)h2b, (const ushort*)wfc1T,
      b_fc1, nullptr, h3b, (int)M2, HF_, C_);
  gemm_bf16<3><<<dim3(6,50),256,0,stream>>>((const ushort*)h3b, (const ushort*)wfc2T,
      b_fc2, x2, out, (int)M2, C_, HF_);
}

// Round 16
// 953.810 us; speedup vs baseline: 1.2612x; 1.0306x over previous
//
#include <hip/hip_runtime.h>
#include <hip/hip_bf16.h>
#include <math.h>

#define INF_ 1e10f
#define LGKM0() asm volatile("s_waitcnt lgkmcnt(0)" ::: "memory")

static constexpr int B_  = 64;
static constexpr int N_  = 197;
static constexpr int C_  = 768;
static constexpr int H_  = 12;
static constexpr int T_  = 196;   // N-1 tokens clustered
static constexpr int KC_ = 98;    // NUM_CLUSTERS
static constexpr int KT_ = 99;    // NUM_CLUSTERS + 1
static constexpr int HF_ = 3072;

static constexpr int N_LN1  = B_*N_;                           // 12608 LN rows
static constexpr int N_PREP = 192 + 1728 + 576 + 2304 + 2304;  // 7104

typedef __attribute__((ext_vector_type(8))) short short8v;
typedef __attribute__((ext_vector_type(4))) float f32x4;
typedef __attribute__((ext_vector_type(4))) int int4v;

__device__ __forceinline__ float wave_sum(float v){
#pragma unroll
  for(int o=32;o;o>>=1) v += __shfl_down(v,o);
  return v;
}

__device__ __forceinline__ ushort f2bf(float v){
  __hip_bfloat16 t = __float2bfloat16(v);
  return *reinterpret_cast<const ushort*>(&t);
}

// Monotone float->u32 (total order matches float <). Key = (val, row, col) lexicographic.
__device__ __forceinline__ unsigned long long packkey(float v, int r, int a){
  unsigned int bb = __float_as_uint(v);
  bb ^= (bb & 0x80000000u) ? 0xFFFFFFFFu : 0x80000000u;
  return ((unsigned long long)bb<<32) | (unsigned)(r<<8) | (unsigned)a;
}
__device__ __forceinline__ float unpackval(unsigned long long key){
  unsigned u = (unsigned)(key>>32);
  u = (u & 0x80000000u) ? (u ^ 0x80000000u) : ~u;
  return __uint_as_float(u);
}

// ---------------- LN body (row = 768, 256 thr); writes f32 and/or bf16 ----------------
__device__ void ln_body(const float* __restrict__ in,
    const float* __restrict__ g, const float* __restrict__ bb,
    float* __restrict__ outf, __hip_bfloat16* __restrict__ outb, int row,
    float* sred, float* sm2){
  int tid = threadIdx.x;
  const float* xr = in + (size_t)row*C_;
  float v0=xr[tid], v1=xr[tid+256], v2=xr[tid+512];
  float s = wave_sum(v0+v1+v2);
  int w=tid>>6, l=tid&63;
  if(l==0) sred[w]=s;
  __syncthreads();
  if(tid==0) sm2[0] = (sred[0]+sred[1]+sred[2]+sred[3])/(float)C_;
  __syncthreads();
  float m = sm2[0];
  float d0=v0-m, d1=v1-m, d2=v2-m;
  float q = wave_sum(d0*d0+d1*d1+d2*d2);
  if(l==0) sred[w]=q;
  __syncthreads();
  if(tid==0) sm2[1] = (sred[0]+sred[1]+sred[2]+sred[3])/(float)C_;
  __syncthreads();
  float sq = sqrtf(sm2[1] + 1e-5f);
  float y0 = d0/sq*g[tid]     + bb[tid];
  float y1 = d1/sq*g[tid+256] + bb[tid+256];
  float y2 = d2/sq*g[tid+512] + bb[tid+512];
  if(outf){
    float* orow = outf + (size_t)row*C_;
    orow[tid]=y0; orow[tid+256]=y1; orow[tid+512]=y2;
  }
  if(outb){
    __hip_bfloat16* orow = outb + (size_t)row*C_;
    orow[tid]=__float2bfloat16(y0); orow[tid+256]=__float2bfloat16(y1); orow[tid+512]=__float2bfloat16(y2);
  }
}

__global__ __launch_bounds__(256) void ln_kernel(const float* __restrict__ in,
    const float* __restrict__ g, const float* __restrict__ bb,
    float* __restrict__ outf, __hip_bfloat16* __restrict__ outb){
  __shared__ float sred[4];
  __shared__ float sm2[2];
  ln_body(in, g, bb, outf, outb, blockIdx.x, sred, sm2);
}

// ---------------- fused LN1 + prep (wmean + 4 weight transposes) ----------------
__global__ __launch_bounds__(256) void ln_prep_kernel(const float* __restrict__ x,
    const float* __restrict__ n1_g, const float* __restrict__ n1_b,
    float* __restrict__ h, __hip_bfloat16* __restrict__ hb,
    const float* __restrict__ w_qkv, const float* __restrict__ w_proj,
    const float* __restrict__ w_fc1, const float* __restrict__ w_fc2,
    float* __restrict__ Wm, __hip_bfloat16* __restrict__ wqkvT,
    __hip_bfloat16* __restrict__ wprojT, __hip_bfloat16* __restrict__ wfc1T,
    __hip_bfloat16* __restrict__ wfc2T){
  __shared__ union { struct { float sred[4]; float sm2[2]; } l; float tile[32][33]; } sh;
  int bid = blockIdx.x;
  int tid = threadIdx.x;
  if(bid < N_LN1){
    ln_body(x, n1_g, n1_b, h, hb, bid, sh.l.sred, sh.l.sm2);
    return;
  }
  bid -= N_LN1;
  if(bid < 192){
    int t = bid*256 + tid;   // t = c*64+d
    if(t >= C_*64) return;
    int c = t>>6, d = t&63;
    const float* p = w_qkv + (size_t)c*(3*C_) + C_ + d;
    float s=0.f;
#pragma unroll
    for(int hh=0;hh<H_;hh++) s += p[hh*64];
    Wm[t] = s*(1.0f/12.0f);
    return;
  }
  bid -= 192;
  const float* w; __hip_bfloat16* wt; int K, N, nbx;
  if(bid < 1728){ w=w_qkv; wt=wqkvT; K=C_; N=3*C_; nbx=72; }
  else if(bid < 1728+576){ bid-=1728; w=w_proj; wt=wprojT; K=C_; N=C_; nbx=24; }
  else if(bid < 1728+576+2304){ bid-=1728+576; w=w_fc1; wt=wfc1T; K=C_; N=HF_; nbx=96; }
  else { bid-=1728+576+2304; w=w_fc2; wt=wfc2T; K=HF_; N=C_; nbx=24; }
  int n0 = (bid%nbx)*32, k0 = (bid/nbx)*32;
  int tx = tid&31, ty = tid>>5;
  for(int r=ty;r<32;r+=8) sh.tile[r][tx] = w[(size_t)(k0+r)*N + n0+tx];
  __syncthreads();
  for(int r=ty;r<32;r+=8) wt[(size_t)(n0+r)*K + k0+tx] = __float2bfloat16(sh.tile[tx][r]);
}

// ---------------- bf16 MFMA GEMM: C = A[MxK] @ Bt[NxK]^T, f32 accum ----------------
// global_load_lds (width 16) async staging into LINEAR LDS tiles [128][32].
// EPI: 1/3 = (res+v)+bias -> f32; 2 = v+bias, exact GELU -> bf16; 4 = store bf16
template<int EPI>
__global__ __launch_bounds__(256) void gemm_bf16(const ushort* __restrict__ A,
    const ushort* __restrict__ Bt, const float* __restrict__ bias,
    const float* __restrict__ res, void* __restrict__ Cout,
    int M, int N, int K){
  constexpr int BM=128, BN=128, BK=32;
  __shared__ ushort As[BM][BK];
  __shared__ ushort Bs[BN][BK];
  int tid = threadIdx.x;
  int bm = blockIdx.y*BM, bn = blockIdx.x*BN;
  int w = tid>>6, l = tid&63;
  int wm = (w>>1)*64, wn = (w&1)*64;
  int lr = l&15, lc = l>>4;           // frag row/col, k-chunk
  f32x4 acc[4][4] = {};
  for(int k0=0;k0<K;k0+=BK){
#pragma unroll
    for(int s=0;s<2;s++){
      int c = s*256 + tid;            // 16B chunk id, 0..511; r=c>>2, q=c&3
      int r = c>>2, q = c&3;
      if(bm + r < M){
        const ushort* srcA = A + (size_t)(bm+r)*K + k0 + q*8;
        __builtin_amdgcn_global_load_lds(
            (const __attribute__((address_space(1))) void*)srcA,
            (__attribute__((address_space(3))) void*)((char*)&As[0][0] + c*16), 16, 0, 0);
      }
      const ushort* srcB = Bt + (size_t)(bn+r)*K + k0 + q*8;
      __builtin_amdgcn_global_load_lds(
          (const __attribute__((address_space(1))) void*)srcB,
          (__attribute__((address_space(3))) void*)((char*)&Bs[0][0] + c*16), 16, 0, 0);
    }
    __syncthreads();                  // drains vmcnt(0) -> LDS ready
    short8v af[4], bfr[4];
#pragma unroll
    for(int f=0; f<4; f++){
      af[f]  = *reinterpret_cast<const short8v*>(&As[wm + f*16 + lr][lc*8]);
      bfr[f] = *reinterpret_cast<const short8v*>(&Bs[wn + f*16 + lr][lc*8]);
    }
#pragma unroll
    for(int i=0;i<4;i++)
#pragma unroll
      for(int j=0;j<4;j++)
        acc[i][j] = __builtin_amdgcn_mfma_f32_16x16x32_bf16(af[i], bfr[j], acc[i][j], 0,0,0);
    __syncthreads();
  }
#pragma unroll
  for(int i=0;i<4;i++){
    int rbase = bm + wm + i*16 + lc*4;
#pragma unroll
    for(int j=0;j<4;j++){
      int col = bn + wn + j*16 + lr;
#pragma unroll
      for(int r=0;r<4;r++){
        int row = rbase + r;
        if(row >= M) continue;
        size_t idx = (size_t)row*N + col;
        float v = acc[i][j][r];
        if constexpr(EPI==1 || EPI==3) ((float*)Cout)[idx] = (res[idx] + v) + bias[col];
        if constexpr(EPI==2){
          v += bias[col];
          v = 0.5f*v*(1.0f+erff(v*0.70710678118654752f));
          ((__hip_bfloat16*)Cout)[idx] = __float2bfloat16(v);
        }
        if constexpr(EPI==4) ((__hip_bfloat16*)Cout)[idx] = __float2bfloat16(v);
      }
    }
  }
}

// ---------------- metric = h @ Wm (f32, sequential k), normalize, drop cls ----------------
__global__ __launch_bounds__(256) void metric_gemm(const float* __restrict__ h,
    const float* __restrict__ Wm, float* __restrict__ mnorm){
  int row0 = blockIdx.x*16;
  __shared__ float hs[16][C_];
  int tid = threadIdx.x;
  int w = tid>>6, l = tid&63;
  for(int t=tid; t<16*C_; t+=256)
    hs[t/C_][t%C_] = h[(size_t)row0*C_ + t];
  __syncthreads();
  float a0=0.f,a1=0.f,a2=0.f,a3=0.f;
#pragma unroll 4
  for(int c=0;c<C_;c++){
    float wv = Wm[c*64+l];
    a0 = fmaf(hs[w*4+0][c], wv, a0);
    a1 = fmaf(hs[w*4+1][c], wv, a1);
    a2 = fmaf(hs[w*4+2][c], wv, a2);
    a3 = fmaf(hs[w*4+3][c], wv, a3);
  }
  float accs[4] = {a0,a1,a2,a3};
#pragma unroll
  for(int r=0;r<4;r++){
    float acc = accs[r];
    float q = acc*acc;
#pragma unroll
    for(int o=32;o;o>>=1) q += __shfl_xor(q,o);
    float nrm = sqrtf(q);
    int row = row0 + w*4 + r;
    int bb = row / N_, n = row - bb*N_;
    if(n>=1) mnorm[((size_t)bb*T_+(n-1))*64+l] = acc/nrm;
  }
}

// ---------------- shared-memory union for the fused cluster||attn kernel ----------------
struct ClusterSh {
  float D[T_][T_+1];
  unsigned long long rowkey[T_];
  unsigned long long gkey[2][4];
  unsigned long long scratch[4];
  float sizes[T_];
  int labels[T_];
  int active[T_];
  int rlist[T_];
  int rcnt;
};
struct AttnSh {
  ushort Ks[208][72];
  ushort VsT[64][232];
  ushort Ps[4][16][232];
  float lsz[208];
};
union FusedSh { ClusterSh c; AttnSh a; };

// ---------------- cluster body: VERBATIM round-9 logic (3 barriers/iter) ----------------
__device__ void cluster_body(ClusterSh& S, const float* __restrict__ mnorm,
    int* __restrict__ labs_ws, float* __restrict__ labs_out, int b){
  int tid = threadIdx.x;
  int w = tid>>6, l = tid&63;
  const float* mb = mnorm + (size_t)b*T_*64;

  for(int t=tid;t<T_*T_;t+=256){
    int r=t/T_, c=t%T_;
    float dot=0.0f;
    for(int d=0;d<64;d++) dot += mb[r*64+d]*mb[c*64+d];
    S.D[r][c] = (r==c) ? INF_ : (1.0f - dot);
  }
  for(int t=tid;t<T_;t+=256){ S.sizes[t]=1.0f; S.labels[t]=t; S.active[t]=1; }
  if(tid<8) S.gkey[tid>>2][tid&3] = ~0ULL;
  __syncthreads();
  if(tid<T_){                    // init row minima (strict < -> first col)
    float bvv=INF_; int ba=0;
    for(int c=0;c<T_;c++){ float v=S.D[tid][c]; if(v<bvv){ bvv=v; ba=c; } }
    S.rowkey[tid] = packkey(bvv, tid, ba);
  }
  __syncthreads();

  for(int it=0; it<T_-KC_; it++){
    int p = it&1;
    unsigned long long key = (tid<T_) ? S.rowkey[tid] : ~0ULL;
    atomicMin(&S.gkey[p][w], key);
    if(tid==0) S.rcnt = 0;
    __syncthreads();                   // b1
    unsigned long long g0=S.gkey[p][0], g1=S.gkey[p][1];
    unsigned long long g2=S.gkey[p][2], g3=S.gkey[p][3];
    unsigned long long ga = g0<g1?g0:g1, gb2 = g2<g3?g2:g3;
    unsigned long long g  = ga<gb2?ga:gb2;
    int i = (int)((g>>8)&0xFF);
    int j = (int)(g&0xFF);
    float ni = S.sizes[i], nj = S.sizes[j];
    int k=tid;
    if(k<T_){
      float di=S.D[i][k], dj=S.D[j][k];
      unsigned long long oldkey = S.rowkey[k];
      float oldrm = unpackval(oldkey);
      int oldarg = (int)(oldkey & 0xFF);
      bool kact = (k!=i) && (k!=j) && (S.active[k]!=0);
      float nd = kact ? (ni*di + nj*dj) / (ni+nj) : INF_;
      S.D[i][k]=nd; S.D[k][i]=nd; S.D[j][k]=INF_; S.D[k][j]=INF_;
      if(S.labels[k]==j) S.labels[k]=i;
      if(k==i){
        int q=atomicAdd(&S.rcnt,1); S.rlist[q]=k;
      } else if(k==j){
        S.rowkey[k] = packkey(INF_, k, 0);
      } else if(kact){
        if(oldarg==i){
          if(nd<=oldrm) S.rowkey[k] = packkey(nd, k, i);
          else { int q=atomicAdd(&S.rcnt,1); S.rlist[q]=k; }
        } else if(oldarg==j){
          if(nd<=oldrm) S.rowkey[k] = packkey(nd, k, i);
          else { int q=atomicAdd(&S.rcnt,1); S.rlist[q]=k; }
        } else {
          if(nd<oldrm || (nd==oldrm && i<oldarg)) S.rowkey[k] = packkey(nd, k, i);
        }
      }
    }
    if(tid==0){ S.sizes[i]=ni+nj; S.active[j]=0; }
    if(l==0) atomicExch(&S.gkey[p^1][w], ~0ULL);
    __syncthreads();                   // b2
    int nr = S.rcnt;
    for(int q=w; q<nr; q+=4){
      int rr = S.rlist[q];
      if(l==0) atomicExch(&S.scratch[w], ~0ULL);
      unsigned long long lk = ~0ULL;
      for(int cc=l; cc<T_; cc+=64){
        unsigned long long ck = packkey(S.D[rr][cc], rr, cc);
        if(ck<lk) lk=ck;
      }
      atomicMin(&S.scratch[w], lk);
      LGKM0();
      unsigned long long rk = S.scratch[w];
      if(l==0) S.rowkey[rr] = rk;
    }
    __syncthreads();                   // b3
  }

  if(tid==0){
    int c=0;
    for(int t=0;t<T_;t++){ c += S.active[t]; S.rlist[t]=c-1; }
    labs_ws[b*N_]=0; labs_out[b*N_]=0.0f;
  }
  __syncthreads();
  for(int t=tid;t<T_;t+=256){
    int lab = S.rlist[S.labels[t]] + 1;
    labs_ws[b*N_+1+t] = lab;
    labs_out[b*N_+1+t] = (float)lab;
  }
}

// ---------------- attn body: VERBATIM round-9 MFMA attention ----------------
__device__ void attn_body(AttnSh& S, const ushort* __restrict__ qkv,
    const float* __restrict__ attn_size, __hip_bfloat16* __restrict__ xa, int h, int b){
  int tid = threadIdx.x;
  int w = tid>>6, l = tid&63;
  int lr = l&15, lc = l>>4;
  const size_t QROW = 3*C_;
  for(int t=tid; t<208*64; t+=256){
    int n=t>>6, d=t&63;
    ushort v = 0;
    if(n<197) v = qkv[((size_t)(b*N_+n))*QROW + C_ + h*64 + d];
    S.Ks[n][d] = v;
  }
  for(int t=tid; t<232*64; t+=256){
    int n=t>>6, d=t&63;
    ushort v = 0;
    if(n<197) v = qkv[((size_t)(b*N_+n))*QROW + 2*C_ + h*64 + d];
    S.VsT[d][n] = v;
  }
  for(int t=tid;t<208;t+=256) S.lsz[t] = (t<197)? logf(attn_size[b*N_+t]) : 0.f;
  for(int c=l; c<16*24; c+=64){ int rr=c/24, cc=208+(c%24); S.Ps[w][rr][cc]=0; }
  __syncthreads();

  for(int qt=w; qt<13; qt+=4){
    int qrow = min(qt*16 + lr, 196);
    const ushort* qp = qkv + ((size_t)(b*N_+qrow))*QROW + h*64;
    short8v aq0 = *reinterpret_cast<const short8v*>(qp + lc*8);
    short8v aq1 = *reinterpret_cast<const short8v*>(qp + 32 + lc*8);
    float sc[13][4];
#pragma unroll
    for(int t=0;t<13;t++){
      short8v b0 = *reinterpret_cast<const short8v*>(&S.Ks[t*16+lr][lc*8]);
      short8v b1 = *reinterpret_cast<const short8v*>(&S.Ks[t*16+lr][32+lc*8]);
      f32x4 a = {0.f,0.f,0.f,0.f};
      a = __builtin_amdgcn_mfma_f32_16x16x32_bf16(aq0, b0, a, 0,0,0);
      a = __builtin_amdgcn_mfma_f32_16x16x32_bf16(aq1, b1, a, 0,0,0);
      float ls = S.lsz[t*16+lr];
      bool mask = (t==12) && (lr>=5);
#pragma unroll
      for(int r=0;r<4;r++) sc[t][r] = mask ? -1e30f : (a[r]*0.125f + ls);
    }
    float rsum[4];
#pragma unroll
    for(int r=0;r<4;r++){
      float m=-1e30f;
#pragma unroll
      for(int t=0;t<13;t++) m = fmaxf(m, sc[t][r]);
#pragma unroll
      for(int o=1;o<16;o<<=1) m = fmaxf(m, __shfl_xor(m,o));
      float s=0.f;
#pragma unroll
      for(int t=0;t<13;t++){ float p=expf(sc[t][r]-m); sc[t][r]=p; s+=p; }
#pragma unroll
      for(int o=1;o<16;o<<=1) s += __shfl_xor(s,o);
      rsum[r]=s;
    }
#pragma unroll
    for(int t=0;t<13;t++)
#pragma unroll
      for(int r=0;r<4;r++)
        S.Ps[w][lc*4+r][t*16+lr] = f2bf(sc[t][r]);
    LGKM0();
    short8v ap[7];
#pragma unroll
    for(int ks=0;ks<7;ks++) ap[ks] = *reinterpret_cast<const short8v*>(&S.Ps[w][lr][ks*32 + lc*8]);
#pragma unroll
    for(int f=0; f<4; f++){
      f32x4 o = {0.f,0.f,0.f,0.f};
#pragma unroll
      for(int ks=0;ks<7;ks++){
        short8v bv = *reinterpret_cast<const short8v*>(&S.VsT[f*16+lr][ks*32 + lc*8]);
        o = __builtin_amdgcn_mfma_f32_16x16x32_bf16(ap[ks], bv, o, 0,0,0);
      }
#pragma unroll
      for(int r=0;r<4;r++){
        int q = qt*16 + lc*4 + r;
        if(q<197) xa[((size_t)(b*N_+q))*C_ + h*64 + f*16 + lr] = __float2bfloat16(o[r]/rsum[r]);
      }
    }
  }
}

// ---------------- fused dispatch: blocks [0,64) cluster, [64, 64+768) attention ----------------
__global__ __launch_bounds__(256) void cluster_attn_fused(
    const float* __restrict__ mnorm, int* __restrict__ labs_ws, float* __restrict__ labs_out,
    const ushort* __restrict__ qkv, const float* __restrict__ attn_size,
    __hip_bfloat16* __restrict__ xa){
  __shared__ FusedSh sh;
  int bid = blockIdx.x;
  if(bid < B_){
    cluster_body(sh.c, mnorm, labs_ws, labs_out, bid);
  } else {
    int idx = bid - B_;
    attn_body(sh.a, qkv, attn_size, xa, idx % H_, idx / H_);
  }
}

// ---------------- weighted-average merge: one block per (chunk of 256 ch, b) ----------------
__global__ __launch_bounds__(256) void merge_kernel(const float* __restrict__ x1,
    const float* __restrict__ asz, const int* __restrict__ labs,
    float* __restrict__ x2, float* __restrict__ size_out){
  int chunk = blockIdx.x;     // 0..2 (C_/256)
  int b = blockIdx.y;
  __shared__ float acc[KT_][256];
  __shared__ int   lab[N_];
  __shared__ float sz[N_];
  __shared__ float ssum[KT_];
  int tid = threadIdx.x;
  for(int t=tid;t<N_;t+=256){ lab[t]=labs[b*N_+t]; sz[t]=asz[b*N_+t]; }
#pragma unroll
  for(int k=0;k<KT_;k++) acc[k][tid]=0.f;
  __syncthreads();
  if(tid<KT_){
    float s=0.f;
    for(int n=0;n<N_;n++) if(lab[n]==tid) s += sz[n];
    ssum[tid]=s;
  }
  int c = chunk*256 + tid;
  const float* xb = x1 + (size_t)b*N_*C_ + c;
  for(int n=0;n<N_;n++){
    float v = xb[(size_t)n*C_];
    int k = lab[n];
    acc[k][tid] += v * sz[n];
  }
  __syncthreads();
  for(int k=0;k<KT_;k++)
    x2[((size_t)(b*KT_+k))*C_ + c] = acc[k][tid] / ssum[k];
  if(chunk==0 && tid<KT_) size_out[b*KT_+tid] = ssum[tid];
}

extern "C" void kernel_launch(void* const* d_in, const int* in_sizes, int n_in,
                              void* d_out, int out_size, void* d_ws, size_t ws_size,
                              hipStream_t stream){
  const float* x      = (const float*)d_in[0];
  const float* asz    = (const float*)d_in[1];
  const float* n1_g   = (const float*)d_in[2];
  const float* n1_b   = (const float*)d_in[3];
  const float* w_qkv  = (const float*)d_in[4];
  const float* w_proj = (const float*)d_in[5];
  const float* b_proj = (const float*)d_in[6];
  const float* n2_g   = (const float*)d_in[7];
  const float* n2_b   = (const float*)d_in[8];
  const float* w_fc1  = (const float*)d_in[9];
  const float* b_fc1  = (const float*)d_in[10];
  const float* w_fc2  = (const float*)d_in[11];
  const float* b_fc2  = (const float*)d_in[12];

  const size_t ROWS = (size_t)B_*N_;        // 12608
  const size_t M2   = (size_t)B_*KT_;       // 6336
  float* ws = (float*)d_ws;

  float* h     = ws;                                    // [ROWS*C] f32 LN1 out; later x1
  float* qkvR  = h + ROWS*C_;                           // region, ROWS*3C floats
  __hip_bfloat16* qkvb = (__hip_bfloat16*)qkvR;         // qkv as bf16 (attn-only consumer)
  float* x2    = qkvR;                                  // [M2*C] alias (qkv dead by merge)
  __hip_bfloat16* h2b = (__hip_bfloat16*)(qkvR + M2*C_);
  __hip_bfloat16* h3b = (__hip_bfloat16*)(qkvR + M2*C_ + M2*C_/2);
  __hip_bfloat16* hb  = (__hip_bfloat16*)(qkvR + ROWS*3*C_);      // [ROWS*C] bf16; later xa
  __hip_bfloat16* xa  = hb;
  float* mnorm = (float*)(hb) + ROWS*C_/2;
  float* Wm    = mnorm + (size_t)B_*T_*64;
  __hip_bfloat16* wqkvT = (__hip_bfloat16*)(Wm + C_*64);
  __hip_bfloat16* wprojT= (__hip_bfloat16*)((float*)wqkvT + (size_t)3*C_*C_/2);
  __hip_bfloat16* wfc1T = (__hip_bfloat16*)((float*)wprojT + (size_t)C_*C_/2);
  __hip_bfloat16* wfc2T = (__hip_bfloat16*)((float*)wfc1T + (size_t)C_*HF_/2);
  int*   labs  = (int*)((float*)wfc2T + (size_t)HF_*C_/2);
  float* x1    = h;

  float* out     = (float*)d_out;
  float* out_sz  = out + M2*C_;
  float* out_lab = out_sz + M2;

  // fused LN1 + prep (wmean + weight transposes) — one dispatch
  ln_prep_kernel<<<dim3(N_LN1 + N_PREP),256,0,stream>>>(x, n1_g, n1_b, h, hb,
      w_qkv, w_proj, w_fc1, w_fc2, Wm, wqkvT, wprojT, wfc1T, wfc2T);

  // attention-block inputs
  gemm_bf16<4><<<dim3(18,99),256,0,stream>>>((const ushort*)hb, (const ushort*)wqkvT,
      nullptr, nullptr, qkvb, (int)ROWS, 3*C_, C_);
  metric_gemm<<<dim3(788),256,0,stream>>>(h, Wm, mnorm);

  // clustering || attention (independent; fused into one dispatch)
  cluster_attn_fused<<<dim3(B_ + H_*B_),256,0,stream>>>(mnorm, labs, out_lab,
      (const ushort*)qkvb, asz, xa);

  gemm_bf16<1><<<dim3(6,99),256,0,stream>>>((const ushort*)xa, (const ushort*)wprojT,
      b_proj, x, x1, (int)ROWS, C_, C_);
  merge_kernel<<<dim3(3,B_),256,0,stream>>>(x1, asz, labs, x2, out_sz);

  // MLP
  ln_kernel<<<dim3((unsigned)M2),256,0,stream>>>(x2, n2_g, n2_b, nullptr, h2b);
  gemm_bf16<2><<<dim3(24,50),256,0,stream>>>((const ushort*)h2b, (const ushort*)wfc1T,
      b_fc1, nullptr, h3b, (int)M2, HF_, C_);
  gemm_bf16<3><<<dim3(6,50),256,0,stream>>>((const ushort*)h3b, (const ushort*)wfc2T,
      b_fc2, x2, out, (int)M2, C_, HF_);
}